// Round 8
// baseline (6972.909 us; speedup 1.0000x reference)
//
#include <hip/hip_runtime.h>
#include <hip/hip_bf16.h>
#include <cmath>

// ---------------------------------------------------------------------------
// Decoder: 27 greedy steps of attention + LSTM + vocab argmax.
// B=64, T=512, H=512, E=512, V=50257, steps=27.
// Round 8: split-bf16 MFMA (hi+lo, 3-product) for spart/gates/logits GEMMs.
// f32 gemm_tile (bank-conflict-fixed) kept for Wh_enc and as full fallback
// when ws_size is too small for the split-weight buffers (~190 MB).
// ---------------------------------------------------------------------------

#define TKK 16

typedef __attribute__((ext_vector_type(8))) short bf16x8;
typedef __attribute__((ext_vector_type(4))) float f32x4;

__device__ inline unsigned short bf16rn(float x) {
  unsigned int u = __float_as_uint(x);
  unsigned int r = u + 0x7fffu + ((u >> 16) & 1u);
  return (unsigned short)(r >> 16);
}
__device__ inline void split1(float x, unsigned short& h, unsigned short& l) {
  h = bf16rn(x);
  float hf = __uint_as_float(((unsigned int)h) << 16);
  l = bf16rn(x - hf);
}

// ---------------- f32 tile GEMM (Wh_enc + fallback) -------------------------
// C[M x N] = A[M x K] * B[N x K]^T. Tile 64x128, 256 thr, thread 4x8.
// Bank fix: thread (tx,ty) owns cols {tx*4..+3} and {64+tx*4..+3} -> 2-way LDS.
__global__ __launch_bounds__(256) void gemm_tile(
    const float* __restrict__ A, int lda,
    const float* __restrict__ B, int ldb,
    float* __restrict__ C, int ldc,
    int Kchunk, long long c_zstride)
{
  __shared__ __align__(16) float At[TKK][68];
  __shared__ __align__(16) float Bt[TKK][132];
  const int tid = threadIdx.x;
  const int tx = tid & 15, ty = tid >> 4;
  const long long mbase = (long long)blockIdx.y * 64;
  const long long nbase = (long long)blockIdx.x * 128;
  const int kbase = blockIdx.z * Kchunk;
  const float* Ap = A + mbase * lda + kbase;
  const float* Bp = B + nbase * ldb + kbase;
  float acc[4][8];
#pragma unroll
  for (int i = 0; i < 4; i++)
#pragma unroll
    for (int j = 0; j < 8; j++) acc[i][j] = 0.f;

  const int lm = tid >> 2;
  const int lk = (tid & 3) << 2;
  for (int k0 = 0; k0 < Kchunk; k0 += TKK) {
    float4 av = *(const float4*)(Ap + (long long)lm * lda + k0 + lk);
    At[lk + 0][lm] = av.x; At[lk + 1][lm] = av.y;
    At[lk + 2][lm] = av.z; At[lk + 3][lm] = av.w;
#pragma unroll
    for (int r = 0; r < 2; r++) {
      int n = (tid + r * 256) >> 2;
      float4 bv = *(const float4*)(Bp + (long long)n * ldb + k0 + lk);
      Bt[lk + 0][n] = bv.x; Bt[lk + 1][n] = bv.y;
      Bt[lk + 2][n] = bv.z; Bt[lk + 3][n] = bv.w;
    }
    __syncthreads();
#pragma unroll
    for (int kk = 0; kk < TKK; ++kk) {
      float4 a4 = *(const float4*)&At[kk][ty * 4];
      float4 b0 = *(const float4*)&Bt[kk][tx * 4];
      float4 b1 = *(const float4*)&Bt[kk][64 + tx * 4];
      float as[4] = {a4.x, a4.y, a4.z, a4.w};
      float bs[8] = {b0.x, b0.y, b0.z, b0.w, b1.x, b1.y, b1.z, b1.w};
#pragma unroll
      for (int i = 0; i < 4; i++)
#pragma unroll
        for (int j = 0; j < 8; j++)
          acc[i][j] = fmaf(as[i], bs[j], acc[i][j]);
    }
    __syncthreads();
  }
  float* Cp = C + (long long)blockIdx.z * c_zstride;
#pragma unroll
  for (int i = 0; i < 4; i++) {
    long long m = mbase + ty * 4 + i;
    float4 v0, v1;
    v0.x = acc[i][0]; v0.y = acc[i][1]; v0.z = acc[i][2]; v0.w = acc[i][3];
    v1.x = acc[i][4]; v1.y = acc[i][5]; v1.z = acc[i][6]; v1.w = acc[i][7];
    *(float4*)(Cp + m * ldc + nbase + tx * 4) = v0;
    *(float4*)(Cp + m * ldc + nbase + 64 + tx * 4) = v1;
  }
}

// ---------------- weight prep ----------------------------------------------
__global__ __launch_bounds__(256) void wcat_kernel(
    const float* __restrict__ W_ih, const float* __restrict__ W_hh,
    float* __restrict__ wcat)
{
  long long fi = (long long)blockIdx.x * 256 + threadIdx.x;
  if (fi >= 2048LL * 1536 / 4) return;
  int k = (int)(fi / 384);
  int c = (int)(fi % 384) * 4;
  float4 v;
  if (c < 1024) v = *(const float4*)(W_ih + (long long)k * 1024 + c);
  else          v = *(const float4*)(W_hh + (long long)k * 512 + (c - 1024));
  *(float4*)(wcat + fi * 4) = v;
}

__global__ __launch_bounds__(256) void wcat_split_kernel(
    const float* __restrict__ W_ih, const float* __restrict__ W_hh,
    unsigned short* __restrict__ whi, unsigned short* __restrict__ wlo)
{
  long long fi = (long long)blockIdx.x * 256 + threadIdx.x;
  if (fi >= 2048LL * 1536 / 4) return;
  int k = (int)(fi / 384);
  int c = (int)(fi % 384) * 4;
  float4 v;
  if (c < 1024) v = *(const float4*)(W_ih + (long long)k * 1024 + c);
  else          v = *(const float4*)(W_hh + (long long)k * 512 + (c - 1024));
  long long e = fi * 4;
  float xs[4] = {v.x, v.y, v.z, v.w};
#pragma unroll
  for (int q = 0; q < 4; q++) {
    unsigned short h, l; split1(xs[q], h, l);
    whi[e + q] = h; wlo[e + q] = l;
  }
}

__global__ __launch_bounds__(256) void split_kernel(
    const float* __restrict__ src, unsigned short* __restrict__ hi,
    unsigned short* __restrict__ lo, long long n)
{
  long long i = (long long)blockIdx.x * 256 + threadIdx.x;
  long long stride = (long long)gridDim.x * 256;
  for (long long e = i * 4; e < n; e += stride * 4) {
    float4 v = *(const float4*)(src + e);
    float xs[4] = {v.x, v.y, v.z, v.w};
#pragma unroll
    for (int q = 0; q < 4; q++) {
      unsigned short h, l; split1(xs[q], h, l);
      hi[e + q] = h; lo[e + q] = l;
    }
  }
}

// ---------------- state init ------------------------------------------------
__global__ __launch_bounds__(256) void init_kernel(
    const float* __restrict__ h0, const float* __restrict__ c0,
    const int* __restrict__ bos,
    float* __restrict__ h, float* __restrict__ c, int* __restrict__ y,
    unsigned short* __restrict__ h_hi, unsigned short* __restrict__ h_lo)
{
  int i = blockIdx.x * 256 + threadIdx.x;
  if (i < 64 * 512) {
    float hv = h0[i];
    h[i] = hv; c[i] = c0[i];
    unsigned short hh, hl; split1(hv, hh, hl);
    h_hi[i] = hh; h_lo[i] = hl;
  }
  if (i < 64) y[i] = bos[0];
}

// ---------------- attention -------------------------------------------------
__global__ __launch_bounds__(256) void scores_kernel(
    const float* __restrict__ whenc,
    const float* __restrict__ spart, int np,
    const float* __restrict__ vvec,
    const int* __restrict__ mask,
    float* __restrict__ scores)
{
  const int b = blockIdx.x, tc = blockIdx.y, tid = threadIdx.x;
  __shared__ __align__(16) float sS[512];
  __shared__ __align__(16) float sV[512];
  for (int i = tid; i < 512; i += 256) {
    float s = 0.f;
    for (int p = 0; p < np; ++p) s += spart[(long long)p * 64 * 512 + b * 512 + i];
    sS[i] = s;
    sV[i] = vvec[i];
  }
  __syncthreads();
  const int wave = tid >> 6, lane = tid & 63;
  const int t0 = tc * 128 + wave * 32;
  for (int tt = 0; tt < 32; ++tt) {
    int t = t0 + tt;
    const float* row = whenc + ((long long)b * 512 + t) * 512;
    float p = 0.f;
#pragma unroll
    for (int u = 0; u < 2; ++u) {
      int hb = u * 256 + lane * 4;
      float4 w = *(const float4*)(row + hb);
      float4 s4 = *(const float4*)&sS[hb];
      float4 v4 = *(const float4*)&sV[hb];
      p = fmaf(v4.x, tanhf(w.x + s4.x), p);
      p = fmaf(v4.y, tanhf(w.y + s4.y), p);
      p = fmaf(v4.z, tanhf(w.z + s4.z), p);
      p = fmaf(v4.w, tanhf(w.w + s4.w), p);
    }
#pragma unroll
    for (int off = 32; off; off >>= 1) p += __shfl_xor(p, off);
    if (lane == 0)
      scores[b * 512 + t] = mask[b * 512 + t] ? p : -1e9f;
  }
}

__global__ __launch_bounds__(256) void ctx_kernel(
    const float* __restrict__ scores,
    const float* __restrict__ enc,
    float* __restrict__ ctxp)
{
  const int b = blockIdx.x, tc = blockIdx.y, tid = threadIdx.x;
  __shared__ float sc[512];
  __shared__ float red[256];
  float l0 = scores[b * 512 + tid];
  float l1 = scores[b * 512 + 256 + tid];
  red[tid] = fmaxf(l0, l1);
  __syncthreads();
  for (int s = 128; s > 0; s >>= 1) {
    if (tid < s) red[tid] = fmaxf(red[tid], red[tid + s]);
    __syncthreads();
  }
  float mx = red[0];
  __syncthreads();
  float e0 = expf(l0 - mx), e1 = expf(l1 - mx);
  sc[tid] = e0; sc[tid + 256] = e1;
  red[tid] = e0 + e1;
  __syncthreads();
  for (int s = 128; s > 0; s >>= 1) {
    if (tid < s) red[tid] += red[tid + s];
    __syncthreads();
  }
  float inv = 1.f / red[0];
  float a0 = 0.f, a1 = 0.f;
  for (int u = 0; u < 128; ++u) {
    int t = tc * 128 + u;
    float w = sc[t] * inv;
    const float* row = enc + ((long long)b * 512 + t) * 512;
    float2 e = *(const float2*)(row + tid * 2);
    a0 = fmaf(w, e.x, a0);
    a1 = fmaf(w, e.y, a1);
  }
  float2 o; o.x = a0; o.y = a1;
  *(float2*)(ctxp + ((long long)(b * 4 + tc)) * 512 + tid * 2) = o;
}

__global__ __launch_bounds__(256) void xbuild_kernel(
    const float* __restrict__ emb, const int* __restrict__ y,
    const float* __restrict__ ctxp, const float* __restrict__ h,
    float* __restrict__ xf,
    unsigned short* __restrict__ xhi, unsigned short* __restrict__ xlo)
{
  const int b = blockIdx.x, tid = threadIdx.x;
  const int yb = y[b];
  for (int i = tid; i < 1536; i += 256) {
    float val;
    if (i < 512) {
      val = emb[(long long)yb * 512 + i];
    } else if (i < 1024) {
      int hh = i - 512;
      val = ctxp[(b * 4 + 0) * 512 + hh] + ctxp[(b * 4 + 1) * 512 + hh]
          + ctxp[(b * 4 + 2) * 512 + hh] + ctxp[(b * 4 + 3) * 512 + hh];
    } else {
      val = h[b * 512 + (i - 1024)];
    }
    if (xf) xf[b * 1536 + i] = val;
    if (xhi) {
      unsigned short hh2, ll2; split1(val, hh2, ll2);
      xhi[b * 1536 + i] = hh2; xlo[b * 1536 + i] = ll2;
    }
  }
}

__global__ __launch_bounds__(512) void lstm_kernel(
    const float* __restrict__ gpart, int ngparts,
    const float* __restrict__ b_ih, const float* __restrict__ b_hh,
    float* __restrict__ h, float* __restrict__ c,
    unsigned short* __restrict__ h_hi, unsigned short* __restrict__ h_lo)
{
  const int b = blockIdx.x, hc = threadIdx.x;
  float g[4];
#pragma unroll
  for (int q = 0; q < 4; q++) {
    int k = q * 512 + hc;
    float s = b_ih[k] + b_hh[k];
    for (int p = 0; p < ngparts; ++p)
      s += gpart[((long long)p * 64 + b) * 2048 + k];
    g[q] = s;
  }
  float ig = 1.f / (1.f + expf(-g[0]));
  float fg = 1.f / (1.f + expf(-g[1]));
  float gg = tanhf(g[2]);
  float og = 1.f / (1.f + expf(-g[3]));
  float c2 = fg * c[b * 512 + hc] + ig * gg;
  float h2 = og * tanhf(c2);
  c[b * 512 + hc] = c2;
  h[b * 512 + hc] = h2;
  if (h_hi) {
    unsigned short hh, hl; split1(h2, hh, hl);
    h_hi[b * 512 + hc] = hh; h_lo[b * 512 + hc] = hl;
  }
}

// ---------------- split-bf16 MFMA GEMMs -------------------------------------
// C[M x N] = A(MxK) * B(NxK)^T, A/B as (hi,lo) bf16. 256 thr = 4 waves,
// tile 64x64; wave w -> A-rows 16w..16w+15, 4 col-frags of 16.
__global__ __launch_bounds__(256) void mfma_gemm(
    const unsigned short* __restrict__ Ahi, const unsigned short* __restrict__ Alo,
    const unsigned short* __restrict__ Bhi, const unsigned short* __restrict__ Blo,
    float* __restrict__ C, int K, int N)
{
  const int tid = threadIdx.x;
  const int w = tid >> 6, l = tid & 63;
  const int arow = blockIdx.y * 64 + w * 16 + (l & 15);
  const int koff = (l >> 4) * 8;
  const int nbase = blockIdx.x * 64;
  f32x4 acc[4];
#pragma unroll
  for (int cf = 0; cf < 4; ++cf) acc[cf] = (f32x4){0.f, 0.f, 0.f, 0.f};

  for (int k0 = 0; k0 < K; k0 += 32) {
    bf16x8 ahi = *(const bf16x8*)(Ahi + (size_t)arow * K + k0 + koff);
    bf16x8 alo = *(const bf16x8*)(Alo + (size_t)arow * K + k0 + koff);
#pragma unroll
    for (int cf = 0; cf < 4; ++cf) {
      int col = nbase + cf * 16 + (l & 15);
      bf16x8 bhi = *(const bf16x8*)(Bhi + (size_t)col * K + k0 + koff);
      bf16x8 blo = *(const bf16x8*)(Blo + (size_t)col * K + k0 + koff);
      acc[cf] = __builtin_amdgcn_mfma_f32_16x16x32_bf16(ahi, bhi, acc[cf], 0, 0, 0);
      acc[cf] = __builtin_amdgcn_mfma_f32_16x16x32_bf16(ahi, blo, acc[cf], 0, 0, 0);
      acc[cf] = __builtin_amdgcn_mfma_f32_16x16x32_bf16(alo, bhi, acc[cf], 0, 0, 0);
    }
  }
#pragma unroll
  for (int cf = 0; cf < 4; ++cf) {
    int col = nbase + cf * 16 + (l & 15);
#pragma unroll
    for (int j = 0; j < 4; ++j) {
      int rowc = blockIdx.y * 64 + w * 16 + (l >> 4) * 4 + j;
      C[(size_t)rowc * N + col] = acc[cf][j];
    }
  }
}

// logits + fused per-block per-batch argmax partial. grid ceil(V/64).
__global__ __launch_bounds__(256) void mfma_logits(
    const unsigned short* __restrict__ Ahi, const unsigned short* __restrict__ Alo,
    const unsigned short* __restrict__ Bhi, const unsigned short* __restrict__ Blo,
    const float* __restrict__ bias, int V, int K,
    float* __restrict__ pval, int* __restrict__ pidx, int nvc)
{
  const int tid = threadIdx.x;
  const int w = tid >> 6, l = tid & 63;
  const int arow = w * 16 + (l & 15);
  const int koff = (l >> 4) * 8;
  const int nbase = blockIdx.x * 64;
  const bf16x8 bz = {0, 0, 0, 0, 0, 0, 0, 0};
  f32x4 acc[4];
#pragma unroll
  for (int cf = 0; cf < 4; ++cf) acc[cf] = (f32x4){0.f, 0.f, 0.f, 0.f};

  for (int k0 = 0; k0 < K; k0 += 32) {
    bf16x8 ahi = *(const bf16x8*)(Ahi + (size_t)arow * K + k0 + koff);
    bf16x8 alo = *(const bf16x8*)(Alo + (size_t)arow * K + k0 + koff);
#pragma unroll
    for (int cf = 0; cf < 4; ++cf) {
      int col = nbase + cf * 16 + (l & 15);
      bf16x8 bhi = bz, blo = bz;
      if (col < V) {
        bhi = *(const bf16x8*)(Bhi + (size_t)col * K + k0 + koff);
        blo = *(const bf16x8*)(Blo + (size_t)col * K + k0 + koff);
      }
      acc[cf] = __builtin_amdgcn_mfma_f32_16x16x32_bf16(ahi, bhi, acc[cf], 0, 0, 0);
      acc[cf] = __builtin_amdgcn_mfma_f32_16x16x32_bf16(ahi, blo, acc[cf], 0, 0, 0);
      acc[cf] = __builtin_amdgcn_mfma_f32_16x16x32_bf16(alo, bhi, acc[cf], 0, 0, 0);
    }
  }
#pragma unroll
  for (int j = 0; j < 4; ++j) {
    float bv = -INFINITY; int bi = 0x7fffffff;
#pragma unroll
    for (int cf = 0; cf < 4; ++cf) {
      int col = nbase + cf * 16 + (l & 15);
      if (col < V) {
        float v = acc[cf][j] + bias[col];
        if (v > bv) { bv = v; bi = col; }
      }
    }
#pragma unroll
    for (int off = 1; off <= 8; off <<= 1) {
      float ov = __shfl_xor(bv, off);
      int oi = __shfl_xor(bi, off);
      if (ov > bv || (ov == bv && oi < bi)) { bv = ov; bi = oi; }
    }
    if ((l & 15) == 0) {
      int b = w * 16 + (l >> 4) * 4 + j;
      pval[b * nvc + blockIdx.x] = bv;
      pidx[b * nvc + blockIdx.x] = bi;
    }
  }
}

// ---------------- fallback f32 logits ---------------------------------------
__global__ __launch_bounds__(256) void logits_kernel(
    const float* __restrict__ A,
    const float* __restrict__ W,
    const float* __restrict__ bias,
    int V, float* __restrict__ pval, int* __restrict__ pidx, int nvc)
{
  __shared__ __align__(16) float At[TKK][68];
  __shared__ __align__(16) float Bt[TKK][132];
  __shared__ float lv[64][16];
  __shared__ int   li[64][16];
  const int tid = threadIdx.x;
  const int tx = tid & 15, ty = tid >> 4;
  const int nbase = blockIdx.x * 128;
  float acc[4][8];
#pragma unroll
  for (int i = 0; i < 4; i++)
#pragma unroll
    for (int j = 0; j < 8; j++) acc[i][j] = 0.f;
  const int lm = tid >> 2;
  const int lk = (tid & 3) << 2;
  for (int k0 = 0; k0 < 512; k0 += TKK) {
    float4 av = *(const float4*)(A + lm * 512 + k0 + lk);
    At[lk + 0][lm] = av.x; At[lk + 1][lm] = av.y;
    At[lk + 2][lm] = av.z; At[lk + 3][lm] = av.w;
#pragma unroll
    for (int r = 0; r < 2; r++) {
      int n = (tid + r * 256) >> 2;
      int ng = nbase + n;
      float4 bv = make_float4(0.f, 0.f, 0.f, 0.f);
      if (ng < V) bv = *(const float4*)(W + (long long)ng * 512 + k0 + lk);
      Bt[lk + 0][n] = bv.x; Bt[lk + 1][n] = bv.y;
      Bt[lk + 2][n] = bv.z; Bt[lk + 3][n] = bv.w;
    }
    __syncthreads();
#pragma unroll
    for (int kk = 0; kk < TKK; ++kk) {
      float4 a4 = *(const float4*)&At[kk][ty * 4];
      float4 b0 = *(const float4*)&Bt[kk][tx * 4];
      float4 b1 = *(const float4*)&Bt[kk][64 + tx * 4];
      float as[4] = {a4.x, a4.y, a4.z, a4.w};
      float bs[8] = {b0.x, b0.y, b0.z, b0.w, b1.x, b1.y, b1.z, b1.w};
#pragma unroll
      for (int i = 0; i < 4; i++)
#pragma unroll
        for (int j = 0; j < 8; j++)
          acc[i][j] = fmaf(as[i], bs[j], acc[i][j]);
    }
    __syncthreads();
  }
#pragma unroll
  for (int i = 0; i < 4; i++) {
    float bv_ = -INFINITY; int bi_ = 0x7fffffff;
#pragma unroll
    for (int j = 0; j < 8; j++) {
      int vg = (j < 4) ? (nbase + tx * 4 + j) : (nbase + 64 + tx * 4 + (j - 4));
      if (vg < V) {
        float val = acc[i][j] + bias[vg];
        if (val > bv_ || (val == bv_ && vg < bi_)) { bv_ = val; bi_ = vg; }
      }
    }
    lv[ty * 4 + i][tx] = bv_; li[ty * 4 + i][tx] = bi_;
  }
  __syncthreads();
  if (tid < 64) {
    float bv_ = -INFINITY; int bi_ = 0x7fffffff;
#pragma unroll
    for (int t = 0; t < 16; t++) {
      if (lv[tid][t] > bv_ || (lv[tid][t] == bv_ && li[tid][t] < bi_)) {
        bv_ = lv[tid][t]; bi_ = li[tid][t];
      }
    }
    pval[tid * nvc + blockIdx.x] = bv_;
    pidx[tid * nvc + blockIdx.x] = bi_;
  }
}

__global__ __launch_bounds__(64) void argfinal_kernel(
    const float* __restrict__ pval, const int* __restrict__ pidx, int nvc,
    int* __restrict__ y, int* __restrict__ out, int step, int steps)
{
  const int b = blockIdx.x, lane = threadIdx.x;
  float bv = -INFINITY; int bi = 0x7fffffff;
  for (int ci = lane; ci < nvc; ci += 64) {
    float v = pval[b * nvc + ci];
    int ix = pidx[b * nvc + ci];
    if (v > bv || (v == bv && ix < bi)) { bv = v; bi = ix; }
  }
#pragma unroll
  for (int off = 32; off; off >>= 1) {
    float ov = __shfl_xor(bv, off);
    int oi = __shfl_xor(bi, off);
    if (ov > bv || (ov == bv && oi < bi)) { bv = ov; bi = oi; }
  }
  if (lane == 0) { y[b] = bi; out[b * steps + step] = bi; }
}

extern "C" void kernel_launch(void* const* d_in, const int* in_sizes, int n_in,
                              void* d_out, int out_size, void* d_ws, size_t ws_size,
                              hipStream_t stream) {
  const float* enc_seq = (const float*)d_in[0];
  const int*   enc_mask = (const int*)d_in[1];
  const float* h0 = (const float*)d_in[2];
  const float* c0 = (const float*)d_in[3];
  const int*   bos = (const int*)d_in[4];
  const float* emb = (const float*)d_in[7];
  const float* W_h = (const float*)d_in[8];
  const float* W_s = (const float*)d_in[9];
  const float* vvec = (const float*)d_in[10];
  const float* W_ih = (const float*)d_in[11];
  const float* W_hh = (const float*)d_in[12];
  const float* b_ih = (const float*)d_in[13];
  const float* b_hh = (const float*)d_in[14];
  const float* W_out = (const float*)d_in[15];
  const float* b_out = (const float*)d_in[16];

  const int B = 64, T = 512, H = 512;
  const int Vn = in_sizes[15] / 512;          // vocab rows of W_out (50257)
  const int steps = out_size / B;             // 27
  int* out = (int*)d_out;

  float* ws = (float*)d_ws;
  size_t off = 0;
  auto alloc = [&](size_t n) { float* p = ws + off; off += (n + 15) & ~(size_t)15; return p; };

  const size_t NEW_NEED = 200ull << 20;       // ~190 MB actually used
  if (ws_size >= NEW_NEED) {
    // ---------------- split-bf16 MFMA path ----------------
    const int NVC = (Vn + 63) / 64;           // 786
    float* whenc  = alloc((size_t)B * T * H);
    float* sbuf   = alloc((size_t)B * T);
    float* spartf = alloc((size_t)B * H);
    float* ctxp   = alloc((size_t)B * 4 * H);
    float* gbuf   = alloc((size_t)B * 2048);
    float* hbuf   = alloc((size_t)B * H);
    float* cbuf   = alloc((size_t)B * H);
    float* pval   = alloc((size_t)B * NVC);
    int*   pidx   = (int*)alloc((size_t)B * NVC);
    int*   ybuf   = (int*)alloc(B);
    unsigned short* h_hi  = (unsigned short*)alloc((size_t)B * H / 2);
    unsigned short* h_lo  = (unsigned short*)alloc((size_t)B * H / 2);
    unsigned short* x_hi  = (unsigned short*)alloc((size_t)B * 1536 / 2);
    unsigned short* x_lo  = (unsigned short*)alloc((size_t)B * 1536 / 2);
    unsigned short* ws_hi = (unsigned short*)alloc(512ull * 512 / 2);
    unsigned short* ws_lo = (unsigned short*)alloc(512ull * 512 / 2);
    unsigned short* wc_hi = (unsigned short*)alloc(2048ull * 1536 / 2);
    unsigned short* wc_lo = (unsigned short*)alloc(2048ull * 1536 / 2);
    unsigned short* wo_hi = (unsigned short*)alloc((size_t)Vn * 512 / 2);
    unsigned short* wo_lo = (unsigned short*)alloc((size_t)Vn * 512 / 2);

    init_kernel<<<128, 256, 0, stream>>>(h0, c0, bos, hbuf, cbuf, ybuf, h_hi, h_lo);
    wcat_split_kernel<<<3072, 256, 0, stream>>>(W_ih, W_hh, wc_hi, wc_lo);
    split_kernel<<<256, 256, 0, stream>>>(W_s, ws_hi, ws_lo, 512ll * 512);
    split_kernel<<<4096, 256, 0, stream>>>(W_out, wo_hi, wo_lo, (long long)Vn * 512);

    gemm_tile<<<dim3(4, 512, 1), 256, 0, stream>>>(
        enc_seq, 512, W_h, 512, whenc, 512, 512, 0);

    for (int step = 0; step < steps; ++step) {
      mfma_gemm<<<dim3(8, 1), 256, 0, stream>>>(h_hi, h_lo, ws_hi, ws_lo,
                                                spartf, 512, 512);
      scores_kernel<<<dim3(64, 4), 256, 0, stream>>>(whenc, spartf, 1, vvec,
                                                     enc_mask, sbuf);
      ctx_kernel<<<dim3(64, 4), 256, 0, stream>>>(sbuf, enc_seq, ctxp);
      xbuild_kernel<<<64, 256, 0, stream>>>(emb, ybuf, ctxp, hbuf,
                                            nullptr, x_hi, x_lo);
      mfma_gemm<<<dim3(32, 1), 256, 0, stream>>>(x_hi, x_lo, wc_hi, wc_lo,
                                                 gbuf, 1536, 2048);
      lstm_kernel<<<64, 512, 0, stream>>>(gbuf, 1, b_ih, b_hh, hbuf, cbuf,
                                          h_hi, h_lo);
      mfma_logits<<<NVC, 256, 0, stream>>>(h_hi, h_lo, wo_hi, wo_lo, b_out,
                                           Vn, 512, pval, pidx, NVC);
      argfinal_kernel<<<64, 64, 0, stream>>>(pval, pidx, NVC, ybuf, out,
                                             step, steps);
    }
  } else {
    // ---------------- fallback: round-7 f32 path ----------------
    const int NVC = (Vn + 127) / 128;
    float* whenc  = alloc((size_t)B * T * H);
    float* sbuf   = alloc((size_t)B * T);
    float* spart  = alloc(4ull * B * H);
    float* ctxp   = alloc((size_t)B * 4 * H);
    float* xbuf   = alloc((size_t)B * 1536);
    float* gpart  = alloc(3ull * B * 2048);
    float* wcat   = alloc(2048ull * 1536);
    float* hbuf   = alloc((size_t)B * H);
    float* cbuf   = alloc((size_t)B * H);
    float* pval   = alloc((size_t)B * NVC);
    int*   ybuf   = (int*)alloc(B);
    int*   pidx   = (int*)alloc((size_t)B * NVC);
    unsigned short* h_hi = (unsigned short*)alloc((size_t)B * H / 2);
    unsigned short* h_lo = (unsigned short*)alloc((size_t)B * H / 2);

    init_kernel<<<128, 256, 0, stream>>>(h0, c0, bos, hbuf, cbuf, ybuf, h_hi, h_lo);
    wcat_kernel<<<3072, 256, 0, stream>>>(W_ih, W_hh, wcat);
    gemm_tile<<<dim3(4, 512, 1), 256, 0, stream>>>(
        enc_seq, 512, W_h, 512, whenc, 512, 512, 0);

    for (int step = 0; step < steps; ++step) {
      gemm_tile<<<dim3(4, 1, 4), 256, 0, stream>>>(
          hbuf, 512, W_s, 512, spart, 512, 128, (long long)B * H);
      scores_kernel<<<dim3(64, 4), 256, 0, stream>>>(whenc, spart, 4, vvec,
                                                     enc_mask, sbuf);
      ctx_kernel<<<dim3(64, 4), 256, 0, stream>>>(sbuf, enc_seq, ctxp);
      xbuild_kernel<<<64, 256, 0, stream>>>(emb, ybuf, ctxp, hbuf,
                                            xbuf, nullptr, nullptr);
      gemm_tile<<<dim3(16, 1, 3), 256, 0, stream>>>(
          xbuf, 1536, wcat, 1536, gpart, 2048, 512, (long long)B * 2048);
      lstm_kernel<<<64, 512, 0, stream>>>(gpart, 3, b_ih, b_hh, hbuf, cbuf,
                                          nullptr, nullptr);
      logits_kernel<<<NVC, 256, 0, stream>>>(hbuf, W_out, b_out, Vn,
                                             pval, pidx, NVC);
      argfinal_kernel<<<64, 64, 0, stream>>>(pval, pidx, NVC, ybuf, out,
                                             step, steps);
    }
  }
}

// Round 10
// 5899.348 us; speedup vs baseline: 1.1820x; 1.1820x over previous
//
#include <hip/hip_runtime.h>
#include <hip/hip_bf16.h>
#include <cmath>

// ---------------------------------------------------------------------------
// Decoder: 27 greedy steps of attention + LSTM + vocab argmax.
// B=64, T=512, H=512, E=512, V=50257, steps=27.
// Round 9: single MFMA path (split-bf16 hi/lo, 3-product). Prefetch-pipelined
// mfma_gemm for the tiny-grid GEMMs; W_out split precomputed if ws fits, else
// split on the fly from f32 inside mfma_logits_fly. Fast exp-based tanh in
// scores. Wh_enc stays f32 gemm_tile (bank-fixed, 226us, feeds every score).
// ---------------------------------------------------------------------------

#define TKK 16

typedef __attribute__((ext_vector_type(8))) short bf16x8;
typedef __attribute__((ext_vector_type(4))) float f32x4;

__device__ inline unsigned short bf16rn(float x) {
  unsigned int u = __float_as_uint(x);
  unsigned int r = u + 0x7fffu + ((u >> 16) & 1u);
  return (unsigned short)(r >> 16);
}
// round-nearest split (used for precomputed splits)
__device__ inline void split1(float x, unsigned short& h, unsigned short& l) {
  h = bf16rn(x);
  float hf = __uint_as_float(((unsigned int)h) << 16);
  l = bf16rn(x - hf);
}
// truncate-hi split (cheaper, used in-kernel): hi err <= 2^-8 rel, compensated
// by the cross terms; residual ~2^-16 rel — far below logit top-2 gaps.
__device__ inline void split_tr(float x, short& h, short& l) {
  unsigned int u = __float_as_uint(x);
  h = (short)(u >> 16);
  float hf = __uint_as_float(u & 0xffff0000u);
  float d = x - hf;
  unsigned int ud = __float_as_uint(d);
  unsigned int r = ud + 0x7fffu + ((ud >> 16) & 1u);
  l = (short)(r >> 16);
}
// tanh = 1 - 2/(e^{2x}+1); exact limits at +/-inf; ~2-3 ulp.
__device__ inline float tanh_fast(float x) {
  float e = __expf(2.f * x);
  return 1.f - 2.f * __builtin_amdgcn_rcpf(e + 1.f);
}

// ---------------- f32 tile GEMM (Wh_enc only) -------------------------------
// C[M x N] = A[M x K] * B[N x K]^T. Tile 64x128, 256 thr, thread 4x8.
// Cols {tx*4, 64+tx*4}: 2-way LDS aliasing (free per m136).
__global__ __launch_bounds__(256) void gemm_tile(
    const float* __restrict__ A, int lda,
    const float* __restrict__ B, int ldb,
    float* __restrict__ C, int ldc,
    int Kchunk, long long c_zstride)
{
  __shared__ __align__(16) float At[TKK][68];
  __shared__ __align__(16) float Bt[TKK][132];
  const int tid = threadIdx.x;
  const int tx = tid & 15, ty = tid >> 4;
  const long long mbase = (long long)blockIdx.y * 64;
  const long long nbase = (long long)blockIdx.x * 128;
  const int kbase = blockIdx.z * Kchunk;
  const float* Ap = A + mbase * lda + kbase;
  const float* Bp = B + nbase * ldb + kbase;
  float acc[4][8];
#pragma unroll
  for (int i = 0; i < 4; i++)
#pragma unroll
    for (int j = 0; j < 8; j++) acc[i][j] = 0.f;

  const int lm = tid >> 2;
  const int lk = (tid & 3) << 2;
  for (int k0 = 0; k0 < Kchunk; k0 += TKK) {
    float4 av = *(const float4*)(Ap + (long long)lm * lda + k0 + lk);
    At[lk + 0][lm] = av.x; At[lk + 1][lm] = av.y;
    At[lk + 2][lm] = av.z; At[lk + 3][lm] = av.w;
#pragma unroll
    for (int r = 0; r < 2; r++) {
      int n = (tid + r * 256) >> 2;
      float4 bv = *(const float4*)(Bp + (long long)n * ldb + k0 + lk);
      Bt[lk + 0][n] = bv.x; Bt[lk + 1][n] = bv.y;
      Bt[lk + 2][n] = bv.z; Bt[lk + 3][n] = bv.w;
    }
    __syncthreads();
#pragma unroll
    for (int kk = 0; kk < TKK; ++kk) {
      float4 a4 = *(const float4*)&At[kk][ty * 4];
      float4 b0 = *(const float4*)&Bt[kk][tx * 4];
      float4 b1 = *(const float4*)&Bt[kk][64 + tx * 4];
      float as[4] = {a4.x, a4.y, a4.z, a4.w};
      float bs[8] = {b0.x, b0.y, b0.z, b0.w, b1.x, b1.y, b1.z, b1.w};
#pragma unroll
      for (int i = 0; i < 4; i++)
#pragma unroll
        for (int j = 0; j < 8; j++)
          acc[i][j] = fmaf(as[i], bs[j], acc[i][j]);
    }
    __syncthreads();
  }
  float* Cp = C + (long long)blockIdx.z * c_zstride;
#pragma unroll
  for (int i = 0; i < 4; i++) {
    long long m = mbase + ty * 4 + i;
    float4 v0, v1;
    v0.x = acc[i][0]; v0.y = acc[i][1]; v0.z = acc[i][2]; v0.w = acc[i][3];
    v1.x = acc[i][4]; v1.y = acc[i][5]; v1.z = acc[i][6]; v1.w = acc[i][7];
    *(float4*)(Cp + m * ldc + nbase + tx * 4) = v0;
    *(float4*)(Cp + m * ldc + nbase + 64 + tx * 4) = v1;
  }
}

// ---------------- weight prep ----------------------------------------------
// Wcat[2048][1536] = [W_ih | W_hh] split to hi/lo bf16.
__global__ __launch_bounds__(256) void wcat_split_kernel(
    const float* __restrict__ W_ih, const float* __restrict__ W_hh,
    unsigned short* __restrict__ whi, unsigned short* __restrict__ wlo)
{
  long long fi = (long long)blockIdx.x * 256 + threadIdx.x;
  if (fi >= 2048LL * 1536 / 4) return;
  int k = (int)(fi / 384);
  int c = (int)(fi % 384) * 4;
  float4 v;
  if (c < 1024) v = *(const float4*)(W_ih + (long long)k * 1024 + c);
  else          v = *(const float4*)(W_hh + (long long)k * 512 + (c - 1024));
  long long e = fi * 4;
  float xs[4] = {v.x, v.y, v.z, v.w};
#pragma unroll
  for (int q = 0; q < 4; q++) {
    unsigned short h, l; split1(xs[q], h, l);
    whi[e + q] = h; wlo[e + q] = l;
  }
}

__global__ __launch_bounds__(256) void split_kernel(
    const float* __restrict__ src, unsigned short* __restrict__ hi,
    unsigned short* __restrict__ lo, long long n)
{
  long long i = (long long)blockIdx.x * 256 + threadIdx.x;
  long long stride = (long long)gridDim.x * 256;
  for (long long e = i * 4; e < n; e += stride * 4) {
    float4 v = *(const float4*)(src + e);
    float xs[4] = {v.x, v.y, v.z, v.w};
#pragma unroll
    for (int q = 0; q < 4; q++) {
      unsigned short h, l; split1(xs[q], h, l);
      hi[e + q] = h; lo[e + q] = l;
    }
  }
}

// ---------------- state init ------------------------------------------------
__global__ __launch_bounds__(256) void init_kernel(
    const float* __restrict__ h0, const float* __restrict__ c0,
    const int* __restrict__ bos,
    float* __restrict__ h, float* __restrict__ c, int* __restrict__ y,
    unsigned short* __restrict__ h_hi, unsigned short* __restrict__ h_lo)
{
  int i = blockIdx.x * 256 + threadIdx.x;
  if (i < 64 * 512) {
    float hv = h0[i];
    h[i] = hv; c[i] = c0[i];
    unsigned short hh, hl; split1(hv, hh, hl);
    h_hi[i] = hh; h_lo[i] = hl;
  }
  if (i < 64) y[i] = bos[0];
}

// ---------------- attention -------------------------------------------------
__global__ __launch_bounds__(256) void scores_kernel(
    const float* __restrict__ whenc,
    const float* __restrict__ sarr,    // [B][H] = h @ W_s^T
    const float* __restrict__ vvec,
    const int* __restrict__ mask,
    float* __restrict__ scores)
{
  const int b = blockIdx.x, tc = blockIdx.y, tid = threadIdx.x;
  __shared__ __align__(16) float sS[512];
  __shared__ __align__(16) float sV[512];
  for (int i = tid; i < 512; i += 256) {
    sS[i] = sarr[b * 512 + i];
    sV[i] = vvec[i];
  }
  __syncthreads();
  const int wave = tid >> 6, lane = tid & 63;
  const int t0 = tc * 128 + wave * 32;
  for (int tt = 0; tt < 32; ++tt) {
    int t = t0 + tt;
    const float* row = whenc + ((long long)b * 512 + t) * 512;
    float p = 0.f;
#pragma unroll
    for (int u = 0; u < 2; ++u) {
      int hb = u * 256 + lane * 4;
      float4 w = *(const float4*)(row + hb);
      float4 s4 = *(const float4*)&sS[hb];
      float4 v4 = *(const float4*)&sV[hb];
      p = fmaf(v4.x, tanh_fast(w.x + s4.x), p);
      p = fmaf(v4.y, tanh_fast(w.y + s4.y), p);
      p = fmaf(v4.z, tanh_fast(w.z + s4.z), p);
      p = fmaf(v4.w, tanh_fast(w.w + s4.w), p);
    }
#pragma unroll
    for (int off = 32; off; off >>= 1) p += __shfl_xor(p, off);
    if (lane == 0)
      scores[b * 512 + t] = mask[b * 512 + t] ? p : -1e9f;
  }
}

__global__ __launch_bounds__(256) void ctx_kernel(
    const float* __restrict__ scores,
    const float* __restrict__ enc,
    float* __restrict__ ctxp)
{
  const int b = blockIdx.x, tc = blockIdx.y, tid = threadIdx.x;
  __shared__ float sc[512];
  __shared__ float red[256];
  float l0 = scores[b * 512 + tid];
  float l1 = scores[b * 512 + 256 + tid];
  red[tid] = fmaxf(l0, l1);
  __syncthreads();
  for (int s = 128; s > 0; s >>= 1) {
    if (tid < s) red[tid] = fmaxf(red[tid], red[tid + s]);
    __syncthreads();
  }
  float mx = red[0];
  __syncthreads();
  float e0 = expf(l0 - mx), e1 = expf(l1 - mx);
  sc[tid] = e0; sc[tid + 256] = e1;
  red[tid] = e0 + e1;
  __syncthreads();
  for (int s = 128; s > 0; s >>= 1) {
    if (tid < s) red[tid] += red[tid + s];
    __syncthreads();
  }
  float inv = 1.f / red[0];
  float a0 = 0.f, a1 = 0.f;
  for (int u = 0; u < 128; ++u) {
    int t = tc * 128 + u;
    float w = sc[t] * inv;
    const float* row = enc + ((long long)b * 512 + t) * 512;
    float2 e = *(const float2*)(row + tid * 2);
    a0 = fmaf(w, e.x, a0);
    a1 = fmaf(w, e.y, a1);
  }
  float2 o; o.x = a0; o.y = a1;
  *(float2*)(ctxp + ((long long)(b * 4 + tc)) * 512 + tid * 2) = o;
}

// x = [emb[y] | sum ctx partials | h], emitted directly as hi/lo bf16.
__global__ __launch_bounds__(256) void xbuild_kernel(
    const float* __restrict__ emb, const int* __restrict__ y,
    const float* __restrict__ ctxp, const float* __restrict__ h,
    unsigned short* __restrict__ xhi, unsigned short* __restrict__ xlo)
{
  const int b = blockIdx.x, tid = threadIdx.x;
  const int yb = y[b];
  for (int i = tid; i < 1536; i += 256) {
    float val;
    if (i < 512) {
      val = emb[(long long)yb * 512 + i];
    } else if (i < 1024) {
      int hh = i - 512;
      val = ctxp[(b * 4 + 0) * 512 + hh] + ctxp[(b * 4 + 1) * 512 + hh]
          + ctxp[(b * 4 + 2) * 512 + hh] + ctxp[(b * 4 + 3) * 512 + hh];
    } else {
      val = h[b * 512 + (i - 1024)];
    }
    unsigned short hh2, ll2; split1(val, hh2, ll2);
    xhi[b * 1536 + i] = hh2; xlo[b * 1536 + i] = ll2;
  }
}

__global__ __launch_bounds__(512) void lstm_kernel(
    const float* __restrict__ gates,   // [B][2048]
    const float* __restrict__ b_ih, const float* __restrict__ b_hh,
    float* __restrict__ h, float* __restrict__ c,
    unsigned short* __restrict__ h_hi, unsigned short* __restrict__ h_lo)
{
  const int b = blockIdx.x, hc = threadIdx.x;
  float g[4];
#pragma unroll
  for (int q = 0; q < 4; q++) {
    int k = q * 512 + hc;
    g[q] = b_ih[k] + b_hh[k] + gates[(long long)b * 2048 + k];
  }
  float ig = 1.f / (1.f + expf(-g[0]));
  float fg = 1.f / (1.f + expf(-g[1]));
  float gg = tanhf(g[2]);
  float og = 1.f / (1.f + expf(-g[3]));
  float c2 = fg * c[b * 512 + hc] + ig * gg;
  float h2 = og * tanhf(c2);
  c[b * 512 + hc] = c2;
  h[b * 512 + hc] = h2;
  unsigned short hh, hl; split1(h2, hh, hl);
  h_hi[b * 512 + hc] = hh; h_lo[b * 512 + hc] = hl;
}

// ---------------- split-bf16 MFMA GEMM (prefetch-pipelined) -----------------
// C[M x N] = A(MxK)*B(NxK)^T, A/B pre-split hi/lo bf16. 256 thr = 4 waves,
// tile 64x64; wave w owns A-rows 16w..16w+15; 4 col-frags of 16.
// Register double-buffer: loads for k0+32 issue before k0's MFMA cluster —
// the spart (8-block) and gates (32-block) grids can't hide latency with
// occupancy, so ILP must.
__global__ __launch_bounds__(256) void mfma_gemm(
    const unsigned short* __restrict__ Ahi, const unsigned short* __restrict__ Alo,
    const unsigned short* __restrict__ Bhi, const unsigned short* __restrict__ Blo,
    float* __restrict__ C, int K, int N)
{
  const int tid = threadIdx.x;
  const int w = tid >> 6, l = tid & 63;
  const int arow = blockIdx.y * 64 + w * 16 + (l & 15);
  const int koff = (l >> 4) * 8;
  const int nbase = blockIdx.x * 64;
  const size_t aoff = (size_t)arow * K + koff;
  size_t boff[4];
#pragma unroll
  for (int cf = 0; cf < 4; ++cf)
    boff[cf] = (size_t)(nbase + cf * 16 + (l & 15)) * K + koff;

  f32x4 acc[4];
#pragma unroll
  for (int cf = 0; cf < 4; ++cf) acc[cf] = (f32x4){0.f, 0.f, 0.f, 0.f};

  bf16x8 ah = *(const bf16x8*)(Ahi + aoff);
  bf16x8 al = *(const bf16x8*)(Alo + aoff);
  bf16x8 bh[4], bl[4];
#pragma unroll
  for (int cf = 0; cf < 4; ++cf) {
    bh[cf] = *(const bf16x8*)(Bhi + boff[cf]);
    bl[cf] = *(const bf16x8*)(Blo + boff[cf]);
  }
  for (int k0 = 0; k0 < K; k0 += 32) {
    bf16x8 ah2 = ah, al2 = al, bh2[4], bl2[4];
#pragma unroll
    for (int cf = 0; cf < 4; ++cf) { bh2[cf] = bh[cf]; bl2[cf] = bl[cf]; }
    if (k0 + 32 < K) {
      ah2 = *(const bf16x8*)(Ahi + aoff + k0 + 32);
      al2 = *(const bf16x8*)(Alo + aoff + k0 + 32);
#pragma unroll
      for (int cf = 0; cf < 4; ++cf) {
        bh2[cf] = *(const bf16x8*)(Bhi + boff[cf] + k0 + 32);
        bl2[cf] = *(const bf16x8*)(Blo + boff[cf] + k0 + 32);
      }
    }
#pragma unroll
    for (int cf = 0; cf < 4; ++cf) {
      acc[cf] = __builtin_amdgcn_mfma_f32_16x16x32_bf16(ah, bh[cf], acc[cf], 0, 0, 0);
      acc[cf] = __builtin_amdgcn_mfma_f32_16x16x32_bf16(ah, bl[cf], acc[cf], 0, 0, 0);
      acc[cf] = __builtin_amdgcn_mfma_f32_16x16x32_bf16(al, bh[cf], acc[cf], 0, 0, 0);
    }
    ah = ah2; al = al2;
#pragma unroll
    for (int cf = 0; cf < 4; ++cf) { bh[cf] = bh2[cf]; bl[cf] = bl2[cf]; }
  }
#pragma unroll
  for (int cf = 0; cf < 4; ++cf) {
    int col = nbase + cf * 16 + (l & 15);
#pragma unroll
    for (int j = 0; j < 4; ++j) {
      int rowc = blockIdx.y * 64 + w * 16 + (l >> 4) * 4 + j;
      C[(size_t)rowc * N + col] = acc[cf][j];
    }
  }
}

// logits + fused per-block per-batch argmax partial, PRE-SPLIT weights.
__global__ __launch_bounds__(256) void mfma_logits_pre(
    const unsigned short* __restrict__ Ahi, const unsigned short* __restrict__ Alo,
    const unsigned short* __restrict__ Bhi, const unsigned short* __restrict__ Blo,
    const float* __restrict__ bias, int V, int K,
    float* __restrict__ pval, int* __restrict__ pidx, int nvc)
{
  const int tid = threadIdx.x;
  const int w = tid >> 6, l = tid & 63;
  const int arow = w * 16 + (l & 15);
  const int koff = (l >> 4) * 8;
  const int nbase = blockIdx.x * 64;
  const bf16x8 bz = {0, 0, 0, 0, 0, 0, 0, 0};
  f32x4 acc[4];
#pragma unroll
  for (int cf = 0; cf < 4; ++cf) acc[cf] = (f32x4){0.f, 0.f, 0.f, 0.f};

  for (int k0 = 0; k0 < K; k0 += 32) {
    bf16x8 ahi = *(const bf16x8*)(Ahi + (size_t)arow * K + k0 + koff);
    bf16x8 alo = *(const bf16x8*)(Alo + (size_t)arow * K + k0 + koff);
#pragma unroll
    for (int cf = 0; cf < 4; ++cf) {
      int col = nbase + cf * 16 + (l & 15);
      bf16x8 bhi = bz, blo = bz;
      if (col < V) {
        bhi = *(const bf16x8*)(Bhi + (size_t)col * K + k0 + koff);
        blo = *(const bf16x8*)(Blo + (size_t)col * K + k0 + koff);
      }
      acc[cf] = __builtin_amdgcn_mfma_f32_16x16x32_bf16(ahi, bhi, acc[cf], 0, 0, 0);
      acc[cf] = __builtin_amdgcn_mfma_f32_16x16x32_bf16(ahi, blo, acc[cf], 0, 0, 0);
      acc[cf] = __builtin_amdgcn_mfma_f32_16x16x32_bf16(alo, bhi, acc[cf], 0, 0, 0);
    }
  }
#pragma unroll
  for (int j = 0; j < 4; ++j) {
    float bv = -INFINITY; int bi = 0x7fffffff;
#pragma unroll
    for (int cf = 0; cf < 4; ++cf) {
      int col = nbase + cf * 16 + (l & 15);
      if (col < V) {
        float v = acc[cf][j] + bias[col];
        if (v > bv) { bv = v; bi = col; }
      }
    }
#pragma unroll
    for (int off = 1; off <= 8; off <<= 1) {
      float ov = __shfl_xor(bv, off);
      int oi = __shfl_xor(bi, off);
      if (ov > bv || (ov == bv && oi < bi)) { bv = ov; bi = oi; }
    }
    if ((l & 15) == 0) {
      int b = w * 16 + (l >> 4) * 4 + j;
      pval[b * nvc + blockIdx.x] = bv;
      pidx[b * nvc + blockIdx.x] = bi;
    }
  }
}

// logits variant reading f32 W_out, splitting in-kernel (used when ws can't
// hold the precomputed 103MB split). Same bytes from memory as the pre path.
__global__ __launch_bounds__(256) void mfma_logits_fly(
    const unsigned short* __restrict__ Ahi, const unsigned short* __restrict__ Alo,
    const float* __restrict__ W,
    const float* __restrict__ bias, int V, int K,
    float* __restrict__ pval, int* __restrict__ pidx, int nvc)
{
  const int tid = threadIdx.x;
  const int w = tid >> 6, l = tid & 63;
  const int arow = w * 16 + (l & 15);
  const int koff = (l >> 4) * 8;
  const int nbase = blockIdx.x * 64;
  const bf16x8 bz = {0, 0, 0, 0, 0, 0, 0, 0};
  f32x4 acc[4];
#pragma unroll
  for (int cf = 0; cf < 4; ++cf) acc[cf] = (f32x4){0.f, 0.f, 0.f, 0.f};

  for (int k0 = 0; k0 < K; k0 += 32) {
    bf16x8 ahi = *(const bf16x8*)(Ahi + (size_t)arow * K + k0 + koff);
    bf16x8 alo = *(const bf16x8*)(Alo + (size_t)arow * K + k0 + koff);
#pragma unroll
    for (int cf = 0; cf < 4; ++cf) {
      int col = nbase + cf * 16 + (l & 15);
      bf16x8 bhi = bz, blo = bz;
      if (col < V) {
        const float* wp = W + (size_t)col * K + k0 + koff;
        float4 fa = *(const float4*)(wp);
        float4 fb = *(const float4*)(wp + 4);
        short h_, l_;
        split_tr(fa.x, h_, l_); bhi[0] = h_; blo[0] = l_;
        split_tr(fa.y, h_, l_); bhi[1] = h_; blo[1] = l_;
        split_tr(fa.z, h_, l_); bhi[2] = h_; blo[2] = l_;
        split_tr(fa.w, h_, l_); bhi[3] = h_; blo[3] = l_;
        split_tr(fb.x, h_, l_); bhi[4] = h_; blo[4] = l_;
        split_tr(fb.y, h_, l_); bhi[5] = h_; blo[5] = l_;
        split_tr(fb.z, h_, l_); bhi[6] = h_; blo[6] = l_;
        split_tr(fb.w, h_, l_); bhi[7] = h_; blo[7] = l_;
      }
      acc[cf] = __builtin_amdgcn_mfma_f32_16x16x32_bf16(ahi, bhi, acc[cf], 0, 0, 0);
      acc[cf] = __builtin_amdgcn_mfma_f32_16x16x32_bf16(ahi, blo, acc[cf], 0, 0, 0);
      acc[cf] = __builtin_amdgcn_mfma_f32_16x16x32_bf16(alo, bhi, acc[cf], 0, 0, 0);
    }
  }
#pragma unroll
  for (int j = 0; j < 4; ++j) {
    float bv = -INFINITY; int bi = 0x7fffffff;
#pragma unroll
    for (int cf = 0; cf < 4; ++cf) {
      int col = nbase + cf * 16 + (l & 15);
      if (col < V) {
        float v = acc[cf][j] + bias[col];
        if (v > bv) { bv = v; bi = col; }
      }
    }
#pragma unroll
    for (int off = 1; off <= 8; off <<= 1) {
      float ov = __shfl_xor(bv, off);
      int oi = __shfl_xor(bi, off);
      if (ov > bv || (ov == bv && oi < bi)) { bv = ov; bi = oi; }
    }
    if ((l & 15) == 0) {
      int b = w * 16 + (l >> 4) * 4 + j;
      pval[b * nvc + blockIdx.x] = bv;
      pidx[b * nvc + blockIdx.x] = bi;
    }
  }
}

__global__ __launch_bounds__(64) void argfinal_kernel(
    const float* __restrict__ pval, const int* __restrict__ pidx, int nvc,
    int* __restrict__ y, int* __restrict__ out, int step, int steps)
{
  const int b = blockIdx.x, lane = threadIdx.x;
  float bv = -INFINITY; int bi = 0x7fffffff;
  for (int ci = lane; ci < nvc; ci += 64) {
    float v = pval[b * nvc + ci];
    int ix = pidx[b * nvc + ci];
    if (v > bv || (v == bv && ix < bi)) { bv = v; bi = ix; }
  }
#pragma unroll
  for (int off = 32; off; off >>= 1) {
    float ov = __shfl_xor(bv, off);
    int oi = __shfl_xor(bi, off);
    if (ov > bv || (ov == bv && oi < bi)) { bv = ov; bi = oi; }
  }
  if (lane == 0) { y[b] = bi; out[b * steps + step] = bi; }
}

extern "C" void kernel_launch(void* const* d_in, const int* in_sizes, int n_in,
                              void* d_out, int out_size, void* d_ws, size_t ws_size,
                              hipStream_t stream) {
  const float* enc_seq = (const float*)d_in[0];
  const int*   enc_mask = (const int*)d_in[1];
  const float* h0 = (const float*)d_in[2];
  const float* c0 = (const float*)d_in[3];
  const int*   bos = (const int*)d_in[4];
  const float* emb = (const float*)d_in[7];
  const float* W_h = (const float*)d_in[8];
  const float* W_s = (const float*)d_in[9];
  const float* vvec = (const float*)d_in[10];
  const float* W_ih = (const float*)d_in[11];
  const float* W_hh = (const float*)d_in[12];
  const float* b_ih = (const float*)d_in[13];
  const float* b_hh = (const float*)d_in[14];
  const float* W_out = (const float*)d_in[15];
  const float* b_out = (const float*)d_in[16];

  const int B = 64, T = 512, H = 512;
  const int Vn = in_sizes[15] / 512;          // 50257
  const int steps = out_size / B;             // 27
  const int NVC = (Vn + 63) / 64;             // 786
  int* out = (int*)d_out;

  float* ws = (float*)d_ws;
  size_t off = 0;
  auto alloc = [&](size_t n) { float* p = ws + off; off += (n + 15) & ~(size_t)15; return p; };

  // ---- base allocations (~83 MB) ----
  float* whenc  = alloc((size_t)B * T * H);
  float* sbuf   = alloc((size_t)B * T);
  float* sarr   = alloc((size_t)B * H);
  float* ctxp   = alloc((size_t)B * 4 * H);
  float* gbuf   = alloc((size_t)B * 2048);
  float* hbuf   = alloc((size_t)B * H);
  float* cbuf   = alloc((size_t)B * H);
  float* pval   = alloc((size_t)B * NVC);
  int*   pidx   = (int*)alloc((size_t)B * NVC);
  int*   ybuf   = (int*)alloc(B);
  unsigned short* h_hi  = (unsigned short*)alloc((size_t)B * H / 2);
  unsigned short* h_lo  = (unsigned short*)alloc((size_t)B * H / 2);
  unsigned short* x_hi  = (unsigned short*)alloc((size_t)B * 1536 / 2);
  unsigned short* x_lo  = (unsigned short*)alloc((size_t)B * 1536 / 2);
  unsigned short* ws_hi = (unsigned short*)alloc(512ull * 512 / 2);
  unsigned short* ws_lo = (unsigned short*)alloc(512ull * 512 / 2);
  unsigned short* wc_hi = (unsigned short*)alloc(2048ull * 1536 / 2);
  unsigned short* wc_lo = (unsigned short*)alloc(2048ull * 1536 / 2);

  // ---- W_out split fits? (103 MB more) ----
  size_t used = off * sizeof(float);
  size_t wo_need = (size_t)Vn * 512 * 2 * sizeof(unsigned short) + (1u << 20);
  bool pre = (ws_size > used) && (ws_size - used >= wo_need);
  unsigned short* wo_hi = nullptr;
  unsigned short* wo_lo = nullptr;
  if (pre) {
    wo_hi = (unsigned short*)alloc((size_t)Vn * 512 / 2);
    wo_lo = (unsigned short*)alloc((size_t)Vn * 512 / 2);
  }

  init_kernel<<<128, 256, 0, stream>>>(h0, c0, bos, hbuf, cbuf, ybuf, h_hi, h_lo);
  wcat_split_kernel<<<3072, 256, 0, stream>>>(W_ih, W_hh, wc_hi, wc_lo);
  split_kernel<<<256, 256, 0, stream>>>(W_s, ws_hi, ws_lo, 512ll * 512);
  if (pre)
    split_kernel<<<4096, 256, 0, stream>>>(W_out, wo_hi, wo_lo, (long long)Vn * 512);

  // Wh_enc (one-time, f32, feeds every score — keep exact)
  gemm_tile<<<dim3(4, 512, 1), 256, 0, stream>>>(
      enc_seq, 512, W_h, 512, whenc, 512, 512, 0);

  for (int step = 0; step < steps; ++step) {
    mfma_gemm<<<dim3(8, 1), 256, 0, stream>>>(h_hi, h_lo, ws_hi, ws_lo,
                                              sarr, 512, 512);
    scores_kernel<<<dim3(64, 4), 256, 0, stream>>>(whenc, sarr, vvec,
                                                   enc_mask, sbuf);
    ctx_kernel<<<dim3(64, 4), 256, 0, stream>>>(sbuf, enc_seq, ctxp);
    xbuild_kernel<<<64, 256, 0, stream>>>(emb, ybuf, ctxp, hbuf, x_hi, x_lo);
    mfma_gemm<<<dim3(32, 1), 256, 0, stream>>>(x_hi, x_lo, wc_hi, wc_lo,
                                               gbuf, 1536, 2048);
    lstm_kernel<<<64, 512, 0, stream>>>(gbuf, b_ih, b_hh, hbuf, cbuf,
                                        h_hi, h_lo);
    if (pre)
      mfma_logits_pre<<<NVC, 256, 0, stream>>>(h_hi, h_lo, wo_hi, wo_lo, b_out,
                                               Vn, 512, pval, pidx, NVC);
    else
      mfma_logits_fly<<<NVC, 256, 0, stream>>>(h_hi, h_lo, W_out, b_out,
                                               Vn, 512, pval, pidx, NVC);
    argfinal_kernel<<<64, 64, 0, stream>>>(pval, pidx, NVC, ybuf, out,
                                           step, steps);
  }
}